// Round 21
// baseline (202.529 us; speedup 1.0000x reference)
//
#include <hip/hip_runtime.h>
#include <hip/hip_fp16.h>
#include <math.h>

#define N_NODES 50000
#define N_EDGES 800000
#define HDIM 128
#define SCAN_B 512
#define SCAN_NB ((N_NODES + SCAN_B - 1) / SCAN_B)   // 98
#define EGRID ((N_EDGES + 255) / 256)               // 3125
#define WT_NB 192
#define GEMM_NB 1024

typedef __attribute__((ext_vector_type(8))) short short8;
typedef __attribute__((ext_vector_type(4))) float f32x4;

// bf16 helpers (manual RNE; bf16->f32 is a 16-bit shift)
__device__ __forceinline__ unsigned int f2bf(float f) {
    unsigned int u = __float_as_uint(f);
    return (u + 0x7fffu + ((u >> 16) & 1u)) >> 16;
}
__device__ __forceinline__ float bf_lo(unsigned int u) { return __uint_as_float(u << 16); }
__device__ __forceinline__ float bf_hi(unsigned int u) { return __uint_as_float(u & 0xffff0000u); }
// fp16 helpers
__device__ __forceinline__ float h2f(unsigned short u) { return __half2float(__ushort_as_half(u)); }
__device__ __forceinline__ unsigned short f2h(float f) { return __half_as_ushort(__float2half_rn(f)); }

// ---------------------------------------------------------------------------
// FUSED dispatch 1: edges (3125 blocks) || wtrans x3 (192 blocks).  (r20)
// ---------------------------------------------------------------------------
__global__ __launch_bounds__(256) void edges_wtrans_k(const int* __restrict__ ei,
                                                      const float* __restrict__ ew,
                                                      int* __restrict__ src32,
                                                      unsigned int* __restrict__ drank,
                                                      unsigned long long* __restrict__ pcnt, int ne,
                                                      const float* __restrict__ W1,
                                                      const float* __restrict__ W2,
                                                      const float* __restrict__ W3,
                                                      unsigned short* __restrict__ Wt1,
                                                      unsigned short* __restrict__ Wt2,
                                                      unsigned short* __restrict__ Wt3) {
    if (blockIdx.x < EGRID) {
        __shared__ int nz;
        if (threadIdx.x == 0) nz = 0;
        __syncthreads();
        int e = blockIdx.x * 256 + threadIdx.x;
        int odd = (e < ne) ? ei[2 * e + 1] : 0;
        if (odd) atomicOr(&nz, 1);
        __syncthreads();
        if (e >= ne) return;
        int s, d;
        if (nz == 0) {  // int64 layout: low words at even offsets
            s = ei[2 * e];
            d = ei[2 * (ne + e)];
        } else {        // int32 layout
            s = ei[e];
            d = ei[ne + e];
        }
        src32[e] = s;
        unsigned int q = __float2uint_rn(ew[e] * 16777216.0f);
        unsigned long long old = atomicAdd(&pcnt[d], (1ULL << 32) | (unsigned long long)q);
        drank[e] = (unsigned int)d | ((unsigned int)(old >> 32) << 16);
    } else {
        int wb = blockIdx.x - EGRID;           // 0..191, 64 blocks per weight
        int which = wb >> 6;
        const float* W = (which == 0) ? W1 : (which == 1) ? W2 : W3;
        unsigned short* Wt = (which == 0) ? Wt1 : (which == 1) ? Wt2 : Wt3;
        int idx = (wb & 63) * 256 + threadIdx.x;   // 0..16383
        int c = idx >> 7, k = idx & 127;
        Wt[idx] = (unsigned short)f2bf(W[k * HDIM + c]);
    }
}

// ---------------------------------------------------------------------------
// Hierarchical exclusive scan (r16). scan1 fuses dinv emit.
// ---------------------------------------------------------------------------
__global__ __launch_bounds__(SCAN_B) void scan1_k(const unsigned long long* __restrict__ pcnt,
                                                  int* __restrict__ incl,
                                                  int* __restrict__ bsum,
                                                  float* __restrict__ dinv, int n) {
    __shared__ int buf[SCAN_B];
    int i = blockIdx.x * SCAN_B + threadIdx.x;
    unsigned long long v64 = (i < n) ? pcnt[i] : 0ULL;
    int v = (int)(v64 >> 32);
    buf[threadIdx.x] = v;
    __syncthreads();
#pragma unroll
    for (int off = 1; off < SCAN_B; off <<= 1) {
        int t = (threadIdx.x >= off) ? buf[threadIdx.x - off] : 0;
        __syncthreads();
        buf[threadIdx.x] += t;
        __syncthreads();
    }
    if (i < n) {
        incl[i] = buf[threadIdx.x];
        float deg = (float)(unsigned int)(v64 & 0xffffffffULL) * (1.0f / 16777216.0f);
        dinv[i] = rsqrtf(deg + 1.0f);
    }
    if (threadIdx.x == SCAN_B - 1) bsum[blockIdx.x] = buf[threadIdx.x];
}

__global__ __launch_bounds__(SCAN_B) void scan3_k(const unsigned long long* __restrict__ pcnt,
                                                  const int* __restrict__ incl,
                                                  const int* __restrict__ bsum,
                                                  int* __restrict__ rowptr, int n, int nb) {
    __shared__ int bs[128];
    if (threadIdx.x < 128) bs[threadIdx.x] = (threadIdx.x < nb) ? bsum[threadIdx.x] : 0;
    __syncthreads();
#pragma unroll
    for (int off = 1; off < 128; off <<= 1) {
        int t = 0;
        if (threadIdx.x < 128 && threadIdx.x >= off) t = bs[threadIdx.x - off];
        __syncthreads();
        if (threadIdx.x < 128) bs[threadIdx.x] += t;
        __syncthreads();
    }
    int i = blockIdx.x * SCAN_B + threadIdx.x;
    if (i < n) {
        int boff = (blockIdx.x == 0) ? 0 : bs[blockIdx.x - 1];
        int c = (int)(pcnt[i] >> 32);
        rowptr[i] = boff + incl[i] - c;
    }
    if (blockIdx.x == 0 && threadIdx.x == 0) rowptr[n] = bs[nb - 1];
}

// ---------------------------------------------------------------------------
// MFMA GEMM body (shared). m89-verified fragment layout (r12).
// ---------------------------------------------------------------------------
template <bool INF16>
__device__ __forceinline__ void gemm_body(const void* __restrict__ Xv,
                                          const unsigned short* __restrict__ Wt,
                                          unsigned short* __restrict__ Y16,
                                          int nrows, int bid, int nb) {
    __shared__ unsigned short WtL[HDIM][136];  // 34.8 KB (+8 pad: 2-way banks only)
    __shared__ unsigned short At[16][136];     // 4.4 KB

    for (int idx = threadIdx.x; idx < HDIM * 16; idx += 256) {
        int row = idx >> 4, q = idx & 15;
        *(uint4*)&WtL[row][q * 8] = *(const uint4*)&Wt[row * HDIM + q * 8];
    }
    __syncthreads();

    const int lane = threadIdx.x & 63;
    const int wave = threadIdx.x >> 6;
    const int col0 = wave * 32 + (lane & 15);
    const int koff = (lane >> 4) * 8;
    const int rsub = (lane >> 4) * 4;

    for (int row0 = bid * 16; row0 < nrows; row0 += nb * 16) {
        {
            int r = threadIdx.x >> 4;
            int c8 = (threadIdx.x & 15) * 8;
            unsigned short tmp[8];
#pragma unroll
            for (int j = 0; j < 8; ++j) tmp[j] = 0;
            if (row0 + r < nrows) {
                if constexpr (INF16) {
                    const unsigned short* Xh = (const unsigned short*)Xv;
                    uint4 v = *(const uint4*)(Xh + (size_t)(row0 + r) * HDIM + c8);
                    unsigned int w[4] = {v.x, v.y, v.z, v.w};
#pragma unroll
                    for (int j = 0; j < 4; ++j) {
                        tmp[2 * j]     = (unsigned short)f2bf(h2f((unsigned short)(w[j] & 0xffffu)));
                        tmp[2 * j + 1] = (unsigned short)f2bf(h2f((unsigned short)(w[j] >> 16)));
                    }
                } else {
                    const float* Xf = (const float*)Xv;
                    const float4* xp = (const float4*)(Xf + (size_t)(row0 + r) * HDIM + c8);
                    float4 v0 = xp[0], v1 = xp[1];
                    tmp[0] = (unsigned short)f2bf(v0.x); tmp[1] = (unsigned short)f2bf(v0.y);
                    tmp[2] = (unsigned short)f2bf(v0.z); tmp[3] = (unsigned short)f2bf(v0.w);
                    tmp[4] = (unsigned short)f2bf(v1.x); tmp[5] = (unsigned short)f2bf(v1.y);
                    tmp[6] = (unsigned short)f2bf(v1.z); tmp[7] = (unsigned short)f2bf(v1.w);
                }
            }
            *(short8*)&At[r][c8] = *(short8*)tmp;
        }
        __syncthreads();

        f32x4 acc0 = {0.f, 0.f, 0.f, 0.f};
        f32x4 acc1 = {0.f, 0.f, 0.f, 0.f};
#pragma unroll
        for (int kb = 0; kb < 4; ++kb) {
            short8 a  = *(const short8*)&At[lane & 15][kb * 32 + koff];
            short8 b0 = *(const short8*)&WtL[col0][kb * 32 + koff];
            short8 b1 = *(const short8*)&WtL[col0 + 16][kb * 32 + koff];
            acc0 = __builtin_amdgcn_mfma_f32_16x16x32_bf16(a, b0, acc0, 0, 0, 0);
            acc1 = __builtin_amdgcn_mfma_f32_16x16x32_bf16(a, b1, acc1, 0, 0, 0);
        }
#pragma unroll
        for (int r = 0; r < 4; ++r) {
            int row = row0 + rsub + r;
            if (row < nrows) {
                Y16[(size_t)row * HDIM + col0]      = (unsigned short)f2bf(acc0[r]);
                Y16[(size_t)row * HDIM + col0 + 16] = (unsigned short)f2bf(acc1[r]);
            }
        }
        __syncthreads();
    }
}

template <bool INF16>
__global__ __launch_bounds__(256) void mfma_gemm_k(const void* __restrict__ Xv,
                                                   const unsigned short* __restrict__ Wt,
                                                   unsigned short* __restrict__ Y16,
                                                   int nrows) {
    gemm_body<INF16>(Xv, Wt, Y16, nrows, blockIdx.x, gridDim.x);
}

// ---------------------------------------------------------------------------
// FUSED dispatch 2: reorder (3125 blocks) || gemm1 (1024 blocks).  (r20)
// ---------------------------------------------------------------------------
__global__ __launch_bounds__(256) void reorder_gemm_k(const int* __restrict__ src,
                                                      const unsigned int* __restrict__ drank,
                                                      const float* __restrict__ ew,
                                                      const float* __restrict__ dinv,
                                                      const int* __restrict__ rowptr,
                                                      unsigned int* __restrict__ csr, int ne,
                                                      const float* __restrict__ x,
                                                      const unsigned short* __restrict__ Wt1,
                                                      unsigned short* __restrict__ Y16, int nrows) {
    if (blockIdx.x < EGRID) {
        int e = blockIdx.x * 256 + threadIdx.x;
        if (e >= ne) return;
        int s = src[e];
        unsigned int dr = drank[e];
        int d = (int)(dr & 0xffffu);
        int rank = (int)(dr >> 16);
        int slot = rowptr[d] + rank;
        float nm = dinv[s] * ew[e] * dinv[d];
        csr[slot] = (unsigned int)s | ((unsigned int)f2h(nm) << 16);
    } else {
        gemm_body<false>(x, Wt1, Y16, nrows, blockIdx.x - EGRID, GEMM_NB);
    }
}

// ---------------------------------------------------------------------------
// Fused CSR gather + finalize, QUARTER-WAVE PER NODE (4 nodes/wave, 16/block):
// each 16-lane quarter reads its row as uint4 (16 x 16B = 256B) -> 4
// independent edge streams per wave (2x MLP vs r18's half-wave) and half the
// load instructions. 8-edge unroll, 4 acc chains (2x float4 each).
// Plain loads (nt caused replay divergence, r13). OUT/RES fp16.
// ---------------------------------------------------------------------------
__device__ __forceinline__ float eluf(float v) { return v > 0.f ? v : expf(v) - 1.f; }

__device__ __forceinline__ void gat_edge4(const unsigned int c,
                                          const uint4* __restrict__ XW4,
                                          int lane16, float4* accA, float4* accB) {
    int sidx = (int)(c & 0xffffu);
    float nm = h2f((unsigned short)(c >> 16));
    uint4 u = XW4[(size_t)sidx * 16 + lane16];
    accA->x += bf_lo(u.x) * nm;
    accA->y += bf_hi(u.x) * nm;
    accA->z += bf_lo(u.y) * nm;
    accA->w += bf_hi(u.y) * nm;
    accB->x += bf_lo(u.z) * nm;
    accB->y += bf_hi(u.z) * nm;
    accB->z += bf_lo(u.w) * nm;
    accB->w += bf_hi(u.w) * nm;
}

__global__ __launch_bounds__(256) void gather_k(const int* __restrict__ rowptr,
                                                const unsigned int* __restrict__ csr,
                                                const uint4* __restrict__ XW4,
                                                const float* __restrict__ dinv,
                                                const float* __restrict__ bias,
                                                const unsigned short* RES,
                                                unsigned short* __restrict__ OUT,
                                                int n) {
    int quarter = threadIdx.x >> 4;    // 0..15
    int lane16 = threadIdx.x & 15;
    int node = blockIdx.x * 16 + quarter;
    if (node >= n) return;
    int s = rowptr[node];
    const int end = rowptr[node + 1];

    float4 a0A = make_float4(0.f, 0.f, 0.f, 0.f), a0B = a0A;
    float4 a1A = a0A, a1B = a0A, a2A = a0A, a2B = a0A, a3A = a0A, a3B = a0A;

    for (; s + 7 < end; s += 8) {
        unsigned int c0 = csr[s];
        unsigned int c1 = csr[s + 1];
        unsigned int c2 = csr[s + 2];
        unsigned int c3 = csr[s + 3];
        unsigned int c4 = csr[s + 4];
        unsigned int c5 = csr[s + 5];
        unsigned int c6 = csr[s + 6];
        unsigned int c7 = csr[s + 7];
        gat_edge4(c0, XW4, lane16, &a0A, &a0B);
        gat_edge4(c1, XW4, lane16, &a1A, &a1B);
        gat_edge4(c2, XW4, lane16, &a2A, &a2B);
        gat_edge4(c3, XW4, lane16, &a3A, &a3B);
        gat_edge4(c4, XW4, lane16, &a0A, &a0B);
        gat_edge4(c5, XW4, lane16, &a1A, &a1B);
        gat_edge4(c6, XW4, lane16, &a2A, &a2B);
        gat_edge4(c7, XW4, lane16, &a3A, &a3B);
    }
    for (; s + 1 < end; s += 2) {
        unsigned int c0 = csr[s];
        unsigned int c1 = csr[s + 1];
        gat_edge4(c0, XW4, lane16, &a0A, &a0B);
        gat_edge4(c1, XW4, lane16, &a1A, &a1B);
    }
    if (s < end) {
        gat_edge4(csr[s], XW4, lane16, &a0A, &a0B);
    }

    float di = dinv[node];
    di = di * di;
    uint4 us = XW4[(size_t)node * 16 + lane16];
    float4 bvA = ((const float4*)bias)[2 * lane16];
    float4 bvB = ((const float4*)bias)[2 * lane16 + 1];
    float4 oA, oB;
    oA.x = eluf(a0A.x + a1A.x + a2A.x + a3A.x + bf_lo(us.x) * di + bvA.x);
    oA.y = eluf(a0A.y + a1A.y + a2A.y + a3A.y + bf_hi(us.x) * di + bvA.y);
    oA.z = eluf(a0A.z + a1A.z + a2A.z + a3A.z + bf_lo(us.y) * di + bvA.z);
    oA.w = eluf(a0A.w + a1A.w + a2A.w + a3A.w + bf_hi(us.y) * di + bvA.w);
    oB.x = eluf(a0B.x + a1B.x + a2B.x + a3B.x + bf_lo(us.z) * di + bvB.x);
    oB.y = eluf(a0B.y + a1B.y + a2B.y + a3B.y + bf_hi(us.z) * di + bvB.y);
    oB.z = eluf(a0B.z + a1B.z + a2B.z + a3B.z + bf_lo(us.w) * di + bvB.z);
    oB.w = eluf(a0B.w + a1B.w + a2B.w + a3B.w + bf_hi(us.w) * di + bvB.w);
    if (RES) {
        uint4 rv = ((const uint4*)RES)[(size_t)node * 16 + lane16];
        oA.x += h2f((unsigned short)(rv.x & 0xffffu));
        oA.y += h2f((unsigned short)(rv.x >> 16));
        oA.z += h2f((unsigned short)(rv.y & 0xffffu));
        oA.w += h2f((unsigned short)(rv.y >> 16));
        oB.x += h2f((unsigned short)(rv.z & 0xffffu));
        oB.y += h2f((unsigned short)(rv.z >> 16));
        oB.z += h2f((unsigned short)(rv.w & 0xffffu));
        oB.w += h2f((unsigned short)(rv.w >> 16));
    }
    uint4 ov;
    ov.x = (unsigned int)f2h(oA.x) | ((unsigned int)f2h(oA.y) << 16);
    ov.y = (unsigned int)f2h(oA.z) | ((unsigned int)f2h(oA.w) << 16);
    ov.z = (unsigned int)f2h(oB.x) | ((unsigned int)f2h(oB.y) << 16);
    ov.w = (unsigned int)f2h(oB.z) | ((unsigned int)f2h(oB.w) << 16);
    ((uint4*)OUT)[(size_t)node * 16 + lane16] = ov;
}

// ---------------------------------------------------------------------------
// Layer-3 gather fused with head (quarter-wave per node; width-16 reduce).
// h3 never hits memory. RES (h2) fp16.
// ---------------------------------------------------------------------------
__global__ __launch_bounds__(256) void gather_head_k(const int* __restrict__ rowptr,
                                                     const unsigned int* __restrict__ csr,
                                                     const uint4* __restrict__ XW4,
                                                     const float* __restrict__ dinv,
                                                     const float* __restrict__ bias,
                                                     const unsigned short* __restrict__ RES,
                                                     const float* __restrict__ Wl,
                                                     const float* __restrict__ bl,
                                                     float* __restrict__ out, int n) {
    int quarter = threadIdx.x >> 4;
    int lane16 = threadIdx.x & 15;
    int node = blockIdx.x * 16 + quarter;
    if (node >= n) return;
    int s = rowptr[node];
    const int end = rowptr[node + 1];

    float4 a0A = make_float4(0.f, 0.f, 0.f, 0.f), a0B = a0A;
    float4 a1A = a0A, a1B = a0A, a2A = a0A, a2B = a0A, a3A = a0A, a3B = a0A;

    for (; s + 7 < end; s += 8) {
        unsigned int c0 = csr[s];
        unsigned int c1 = csr[s + 1];
        unsigned int c2 = csr[s + 2];
        unsigned int c3 = csr[s + 3];
        unsigned int c4 = csr[s + 4];
        unsigned int c5 = csr[s + 5];
        unsigned int c6 = csr[s + 6];
        unsigned int c7 = csr[s + 7];
        gat_edge4(c0, XW4, lane16, &a0A, &a0B);
        gat_edge4(c1, XW4, lane16, &a1A, &a1B);
        gat_edge4(c2, XW4, lane16, &a2A, &a2B);
        gat_edge4(c3, XW4, lane16, &a3A, &a3B);
        gat_edge4(c4, XW4, lane16, &a0A, &a0B);
        gat_edge4(c5, XW4, lane16, &a1A, &a1B);
        gat_edge4(c6, XW4, lane16, &a2A, &a2B);
        gat_edge4(c7, XW4, lane16, &a3A, &a3B);
    }
    for (; s + 1 < end; s += 2) {
        unsigned int c0 = csr[s];
        unsigned int c1 = csr[s + 1];
        gat_edge4(c0, XW4, lane16, &a0A, &a0B);
        gat_edge4(c1, XW4, lane16, &a1A, &a1B);
    }
    if (s < end) {
        gat_edge4(csr[s], XW4, lane16, &a0A, &a0B);
    }

    float di = dinv[node];
    di = di * di;
    uint4 us = XW4[(size_t)node * 16 + lane16];
    float4 bvA = ((const float4*)bias)[2 * lane16];
    float4 bvB = ((const float4*)bias)[2 * lane16 + 1];
    uint4 rv = ((const uint4*)RES)[(size_t)node * 16 + lane16];
    float4 oA, oB;
    oA.x = eluf(a0A.x + a1A.x + a2A.x + a3A.x + bf_lo(us.x) * di + bvA.x) + h2f((unsigned short)(rv.x & 0xffffu));
    oA.y = eluf(a0A.y + a1A.y + a2A.y + a3A.y + bf_hi(us.x) * di + bvA.y) + h2f((unsigned short)(rv.x >> 16));
    oA.z = eluf(a0A.z + a1A.z + a2A.z + a3A.z + bf_lo(us.y) * di + bvA.z) + h2f((unsigned short)(rv.y & 0xffffu));
    oA.w = eluf(a0A.w + a1A.w + a2A.w + a3A.w + bf_hi(us.y) * di + bvA.w) + h2f((unsigned short)(rv.y >> 16));
    oB.x = eluf(a0B.x + a1B.x + a2B.x + a3B.x + bf_lo(us.z) * di + bvB.x) + h2f((unsigned short)(rv.z & 0xffffu));
    oB.y = eluf(a0B.y + a1B.y + a2B.y + a3B.y + bf_hi(us.z) * di + bvB.y) + h2f((unsigned short)(rv.z >> 16));
    oB.z = eluf(a0B.z + a1B.z + a2B.z + a3B.z + bf_lo(us.w) * di + bvB.z) + h2f((unsigned short)(rv.w & 0xffffu));
    oB.w = eluf(a0B.w + a1B.w + a2B.w + a3B.w + bf_hi(us.w) * di + bvB.w) + h2f((unsigned short)(rv.w >> 16));

    float4 wvA = ((const float4*)Wl)[2 * lane16];
    float4 wvB = ((const float4*)Wl)[2 * lane16 + 1];
    float acc = oA.x * wvA.x + oA.y * wvA.y + oA.z * wvA.z + oA.w * wvA.w
              + oB.x * wvB.x + oB.y * wvB.y + oB.z * wvB.z + oB.w * wvB.w;
#pragma unroll
    for (int off = 8; off > 0; off >>= 1) acc += __shfl_down(acc, off, 16);
    if (lane16 == 0) out[node] = 1.f / (1.f + expf(-(acc + bl[0])));
}

// ---------------------------------------------------------------------------
extern "C" void kernel_launch(void* const* d_in, const int* in_sizes, int n_in,
                              void* d_out, int out_size, void* d_ws, size_t ws_size,
                              hipStream_t stream) {
    const float* x  = (const float*)d_in[0];
    const int*   ei = (const int*)d_in[1];
    const float* ew = (const float*)d_in[2];
    const float* W1 = (const float*)d_in[3];
    const float* b1 = (const float*)d_in[4];
    const float* W2 = (const float*)d_in[5];
    const float* b2 = (const float*)d_in[6];
    const float* W3 = (const float*)d_in[7];
    const float* b3 = (const float*)d_in[8];
    const float* Wl = (const float*)d_in[9];
    const float* bl = (const float*)d_in[10];
    float* out = (float*)d_out;

    char* ws = (char*)d_ws;
    const size_t NHB = (size_t)N_NODES * HDIM * sizeof(float);  // 25.6 MB slots
    unsigned int*   A = (unsigned int*)(ws);          // XW in bf16 (12.8 MB used)
    unsigned short* B = (unsigned short*)(ws + NHB);  // h1 (fp16)
    unsigned short* C = (unsigned short*)(ws + 2 * NHB);  // h2 (fp16)
    char*  p    = ws + 3 * NHB;
    unsigned long long* pcnt = (unsigned long long*)p; p += sizeof(unsigned long long) * N_NODES;
    float* dinv    = (float*)p;            p += sizeof(float) * N_NODES;
    int*   src32   = (int*)p;              p += sizeof(int) * N_EDGES;
    unsigned int* drank = (unsigned int*)p; p += sizeof(unsigned int) * N_EDGES;
    int*   incl    = (int*)p;              p += sizeof(int) * N_NODES;
    int*   rowptr  = (int*)p;              p += sizeof(int) * (N_NODES + 2);
    unsigned int* csr = (unsigned int*)p;  p += sizeof(unsigned int) * N_EDGES;
    unsigned short* Wt1 = (unsigned short*)p; p += sizeof(unsigned short) * HDIM * HDIM;
    unsigned short* Wt2 = (unsigned short*)p; p += sizeof(unsigned short) * HDIM * HDIM;
    unsigned short* Wt3 = (unsigned short*)p; p += sizeof(unsigned short) * HDIM * HDIM;
    int*   bsum    = (int*)p;              p += sizeof(int) * 128;

    const int TB = 256;
    const int ggrid = (N_NODES + 15) / 16;  // 16 nodes per block (quarter-wave each)

    // --- preprocessing: [edges || wtrans] -> scan -> [reorder || gemm1] ---
    hipMemsetAsync(pcnt, 0, N_NODES * sizeof(unsigned long long), stream);
    edges_wtrans_k<<<EGRID + WT_NB, TB, 0, stream>>>(ei, ew, src32, drank, pcnt, N_EDGES,
                                                     W1, W2, W3, Wt1, Wt2, Wt3);
    scan1_k<<<SCAN_NB, SCAN_B, 0, stream>>>(pcnt, incl, bsum, dinv, N_NODES);
    scan3_k<<<SCAN_NB, SCAN_B, 0, stream>>>(pcnt, incl, bsum, rowptr, N_NODES, SCAN_NB);
    reorder_gemm_k<<<EGRID + GEMM_NB, TB, 0, stream>>>(src32, drank, ew, dinv, rowptr, csr, N_EDGES,
                                                       x, Wt1, (unsigned short*)A, N_NODES);

    // --- layer 1: h1 = elu(gcn(x, W1, b1)) -> B (fp16)  [gemm1 already done] ---
    gather_k<<<ggrid, TB, 0, stream>>>(rowptr, csr, (const uint4*)A, dinv, b1, nullptr, B, N_NODES);

    // --- layer 2: h2 = elu(gcn(h1, W2, b2)) + h1 -> C (fp16) ---
    mfma_gemm_k<true><<<GEMM_NB, TB, 0, stream>>>(B, Wt2, (unsigned short*)A, N_NODES);
    gather_k<<<ggrid, TB, 0, stream>>>(rowptr, csr, (const uint4*)A, dinv, b2, B, C, N_NODES);

    // --- layer 3 + head fused: out = sigmoid((elu(gcn(h2,W3,b3))+h2) @ Wl + bl) ---
    mfma_gemm_k<true><<<GEMM_NB, TB, 0, stream>>>(C, Wt3, (unsigned short*)A, N_NODES);
    gather_head_k<<<ggrid, TB, 0, stream>>>(rowptr, csr, (const uint4*)A, dinv, b3, C, Wl, bl, out, N_NODES);
}

// Round 22
// 198.229 us; speedup vs baseline: 1.0217x; 1.0217x over previous
//
#include <hip/hip_runtime.h>
#include <hip/hip_fp16.h>
#include <math.h>

#define N_NODES 50000
#define N_EDGES 800000
#define HDIM 128
#define SCAN_B 512
#define SCAN_NB ((N_NODES + SCAN_B - 1) / SCAN_B)   // 98
#define EGRID ((N_EDGES + 255) / 256)               // 3125
#define WT_NB 192
#define GEMM_NB 1024

typedef __attribute__((ext_vector_type(8))) short short8;
typedef __attribute__((ext_vector_type(4))) float f32x4;

// bf16 helpers (manual RNE; bf16->f32 is a 16-bit shift)
__device__ __forceinline__ unsigned int f2bf(float f) {
    unsigned int u = __float_as_uint(f);
    return (u + 0x7fffu + ((u >> 16) & 1u)) >> 16;
}
__device__ __forceinline__ float bf_lo(unsigned int u) { return __uint_as_float(u << 16); }
__device__ __forceinline__ float bf_hi(unsigned int u) { return __uint_as_float(u & 0xffff0000u); }
// fp16 helpers
__device__ __forceinline__ float h2f(unsigned short u) { return __half2float(__ushort_as_half(u)); }
__device__ __forceinline__ unsigned short f2h(float f) { return __half_as_ushort(__float2half_rn(f)); }

// ---------------------------------------------------------------------------
// FUSED dispatch 1: edges (3125 blocks) || wtrans x3 (192 blocks).  (r20)
// ---------------------------------------------------------------------------
__global__ __launch_bounds__(256) void edges_wtrans_k(const int* __restrict__ ei,
                                                      const float* __restrict__ ew,
                                                      int* __restrict__ src32,
                                                      unsigned int* __restrict__ drank,
                                                      unsigned long long* __restrict__ pcnt, int ne,
                                                      const float* __restrict__ W1,
                                                      const float* __restrict__ W2,
                                                      const float* __restrict__ W3,
                                                      unsigned short* __restrict__ Wt1,
                                                      unsigned short* __restrict__ Wt2,
                                                      unsigned short* __restrict__ Wt3) {
    if (blockIdx.x < EGRID) {
        __shared__ int nz;
        if (threadIdx.x == 0) nz = 0;
        __syncthreads();
        int e = blockIdx.x * 256 + threadIdx.x;
        int odd = (e < ne) ? ei[2 * e + 1] : 0;
        if (odd) atomicOr(&nz, 1);
        __syncthreads();
        if (e >= ne) return;
        int s, d;
        if (nz == 0) {  // int64 layout: low words at even offsets
            s = ei[2 * e];
            d = ei[2 * (ne + e)];
        } else {        // int32 layout
            s = ei[e];
            d = ei[ne + e];
        }
        src32[e] = s;
        unsigned int q = __float2uint_rn(ew[e] * 16777216.0f);
        unsigned long long old = atomicAdd(&pcnt[d], (1ULL << 32) | (unsigned long long)q);
        drank[e] = (unsigned int)d | ((unsigned int)(old >> 32) << 16);
    } else {
        int wb = blockIdx.x - EGRID;           // 0..191, 64 blocks per weight
        int which = wb >> 6;
        const float* W = (which == 0) ? W1 : (which == 1) ? W2 : W3;
        unsigned short* Wt = (which == 0) ? Wt1 : (which == 1) ? Wt2 : Wt3;
        int idx = (wb & 63) * 256 + threadIdx.x;   // 0..16383
        int c = idx >> 7, k = idx & 127;
        Wt[idx] = (unsigned short)f2bf(W[k * HDIM + c]);
    }
}

// ---------------------------------------------------------------------------
// Hierarchical exclusive scan (r16). scan1 fuses dinv emit.
// ---------------------------------------------------------------------------
__global__ __launch_bounds__(SCAN_B) void scan1_k(const unsigned long long* __restrict__ pcnt,
                                                  int* __restrict__ incl,
                                                  int* __restrict__ bsum,
                                                  float* __restrict__ dinv, int n) {
    __shared__ int buf[SCAN_B];
    int i = blockIdx.x * SCAN_B + threadIdx.x;
    unsigned long long v64 = (i < n) ? pcnt[i] : 0ULL;
    int v = (int)(v64 >> 32);
    buf[threadIdx.x] = v;
    __syncthreads();
#pragma unroll
    for (int off = 1; off < SCAN_B; off <<= 1) {
        int t = (threadIdx.x >= off) ? buf[threadIdx.x - off] : 0;
        __syncthreads();
        buf[threadIdx.x] += t;
        __syncthreads();
    }
    if (i < n) {
        incl[i] = buf[threadIdx.x];
        float deg = (float)(unsigned int)(v64 & 0xffffffffULL) * (1.0f / 16777216.0f);
        dinv[i] = rsqrtf(deg + 1.0f);
    }
    if (threadIdx.x == SCAN_B - 1) bsum[blockIdx.x] = buf[threadIdx.x];
}

__global__ __launch_bounds__(SCAN_B) void scan3_k(const unsigned long long* __restrict__ pcnt,
                                                  const int* __restrict__ incl,
                                                  const int* __restrict__ bsum,
                                                  int* __restrict__ rowptr, int n, int nb) {
    __shared__ int bs[128];
    if (threadIdx.x < 128) bs[threadIdx.x] = (threadIdx.x < nb) ? bsum[threadIdx.x] : 0;
    __syncthreads();
#pragma unroll
    for (int off = 1; off < 128; off <<= 1) {
        int t = 0;
        if (threadIdx.x < 128 && threadIdx.x >= off) t = bs[threadIdx.x - off];
        __syncthreads();
        if (threadIdx.x < 128) bs[threadIdx.x] += t;
        __syncthreads();
    }
    int i = blockIdx.x * SCAN_B + threadIdx.x;
    if (i < n) {
        int boff = (blockIdx.x == 0) ? 0 : bs[blockIdx.x - 1];
        int c = (int)(pcnt[i] >> 32);
        rowptr[i] = boff + incl[i] - c;
    }
    if (blockIdx.x == 0 && threadIdx.x == 0) rowptr[n] = bs[nb - 1];
}

// ---------------------------------------------------------------------------
// MFMA GEMM body (shared). m89-verified fragment layout (r12).
// ---------------------------------------------------------------------------
template <bool INF16>
__device__ __forceinline__ void gemm_body(const void* __restrict__ Xv,
                                          const unsigned short* __restrict__ Wt,
                                          unsigned short* __restrict__ Y16,
                                          int nrows, int bid, int nb) {
    __shared__ unsigned short WtL[HDIM][136];  // 34.8 KB (+8 pad: 2-way banks only)
    __shared__ unsigned short At[16][136];     // 4.4 KB

    for (int idx = threadIdx.x; idx < HDIM * 16; idx += 256) {
        int row = idx >> 4, q = idx & 15;
        *(uint4*)&WtL[row][q * 8] = *(const uint4*)&Wt[row * HDIM + q * 8];
    }
    __syncthreads();

    const int lane = threadIdx.x & 63;
    const int wave = threadIdx.x >> 6;
    const int col0 = wave * 32 + (lane & 15);
    const int koff = (lane >> 4) * 8;
    const int rsub = (lane >> 4) * 4;

    for (int row0 = bid * 16; row0 < nrows; row0 += nb * 16) {
        {
            int r = threadIdx.x >> 4;
            int c8 = (threadIdx.x & 15) * 8;
            unsigned short tmp[8];
#pragma unroll
            for (int j = 0; j < 8; ++j) tmp[j] = 0;
            if (row0 + r < nrows) {
                if constexpr (INF16) {
                    const unsigned short* Xh = (const unsigned short*)Xv;
                    uint4 v = *(const uint4*)(Xh + (size_t)(row0 + r) * HDIM + c8);
                    unsigned int w[4] = {v.x, v.y, v.z, v.w};
#pragma unroll
                    for (int j = 0; j < 4; ++j) {
                        tmp[2 * j]     = (unsigned short)f2bf(h2f((unsigned short)(w[j] & 0xffffu)));
                        tmp[2 * j + 1] = (unsigned short)f2bf(h2f((unsigned short)(w[j] >> 16)));
                    }
                } else {
                    const float* Xf = (const float*)Xv;
                    const float4* xp = (const float4*)(Xf + (size_t)(row0 + r) * HDIM + c8);
                    float4 v0 = xp[0], v1 = xp[1];
                    tmp[0] = (unsigned short)f2bf(v0.x); tmp[1] = (unsigned short)f2bf(v0.y);
                    tmp[2] = (unsigned short)f2bf(v0.z); tmp[3] = (unsigned short)f2bf(v0.w);
                    tmp[4] = (unsigned short)f2bf(v1.x); tmp[5] = (unsigned short)f2bf(v1.y);
                    tmp[6] = (unsigned short)f2bf(v1.z); tmp[7] = (unsigned short)f2bf(v1.w);
                }
            }
            *(short8*)&At[r][c8] = *(short8*)tmp;
        }
        __syncthreads();

        f32x4 acc0 = {0.f, 0.f, 0.f, 0.f};
        f32x4 acc1 = {0.f, 0.f, 0.f, 0.f};
#pragma unroll
        for (int kb = 0; kb < 4; ++kb) {
            short8 a  = *(const short8*)&At[lane & 15][kb * 32 + koff];
            short8 b0 = *(const short8*)&WtL[col0][kb * 32 + koff];
            short8 b1 = *(const short8*)&WtL[col0 + 16][kb * 32 + koff];
            acc0 = __builtin_amdgcn_mfma_f32_16x16x32_bf16(a, b0, acc0, 0, 0, 0);
            acc1 = __builtin_amdgcn_mfma_f32_16x16x32_bf16(a, b1, acc1, 0, 0, 0);
        }
#pragma unroll
        for (int r = 0; r < 4; ++r) {
            int row = row0 + rsub + r;
            if (row < nrows) {
                Y16[(size_t)row * HDIM + col0]      = (unsigned short)f2bf(acc0[r]);
                Y16[(size_t)row * HDIM + col0 + 16] = (unsigned short)f2bf(acc1[r]);
            }
        }
        __syncthreads();
    }
}

template <bool INF16>
__global__ __launch_bounds__(256) void mfma_gemm_k(const void* __restrict__ Xv,
                                                   const unsigned short* __restrict__ Wt,
                                                   unsigned short* __restrict__ Y16,
                                                   int nrows) {
    gemm_body<INF16>(Xv, Wt, Y16, nrows, blockIdx.x, gridDim.x);
}

// ---------------------------------------------------------------------------
// FUSED dispatch 2: reorder (3125 blocks) || gemm1 (1024 blocks).  (r20)
// ---------------------------------------------------------------------------
__global__ __launch_bounds__(256) void reorder_gemm_k(const int* __restrict__ src,
                                                      const unsigned int* __restrict__ drank,
                                                      const float* __restrict__ ew,
                                                      const float* __restrict__ dinv,
                                                      const int* __restrict__ rowptr,
                                                      unsigned int* __restrict__ csr, int ne,
                                                      const float* __restrict__ x,
                                                      const unsigned short* __restrict__ Wt1,
                                                      unsigned short* __restrict__ Y16, int nrows) {
    if (blockIdx.x < EGRID) {
        int e = blockIdx.x * 256 + threadIdx.x;
        if (e >= ne) return;
        int s = src[e];
        unsigned int dr = drank[e];
        int d = (int)(dr & 0xffffu);
        int rank = (int)(dr >> 16);
        int slot = rowptr[d] + rank;
        float nm = dinv[s] * ew[e] * dinv[d];
        csr[slot] = (unsigned int)s | ((unsigned int)f2h(nm) << 16);
    } else {
        gemm_body<false>(x, Wt1, Y16, nrows, blockIdx.x - EGRID, GEMM_NB);
    }
}

// ---------------------------------------------------------------------------
// Fused CSR gather + finalize, HALF-WAVE PER NODE (2 nodes/wave, 8/block):
// r18's proven-optimal MLP point (r21's quarter-wave regressed). Each 32-lane
// half reads its row as uint2 (32 x 8B = 256B). 8-edge unroll, 4 acc chains.
// Plain loads (nt caused replay divergence, r13). OUT/RES fp16.
// ---------------------------------------------------------------------------
__device__ __forceinline__ float eluf(float v) { return v > 0.f ? v : expf(v) - 1.f; }

__device__ __forceinline__ void gat_edge2(const unsigned int c,
                                          const uint2* __restrict__ XW2,
                                          int lane32, float4* acc) {
    int sidx = (int)(c & 0xffffu);
    float nm = h2f((unsigned short)(c >> 16));
    uint2 u = XW2[(size_t)sidx * 32 + lane32];
    acc->x += bf_lo(u.x) * nm;
    acc->y += bf_hi(u.x) * nm;
    acc->z += bf_lo(u.y) * nm;
    acc->w += bf_hi(u.y) * nm;
}

__global__ __launch_bounds__(256) void gather_k(const int* __restrict__ rowptr,
                                                const unsigned int* __restrict__ csr,
                                                const uint2* __restrict__ XW2,
                                                const float* __restrict__ dinv,
                                                const float* __restrict__ bias,
                                                const unsigned short* RES,
                                                unsigned short* __restrict__ OUT,
                                                int n) {
    int half = threadIdx.x >> 5;       // 0..7
    int lane32 = threadIdx.x & 31;
    int node = blockIdx.x * 8 + half;
    if (node >= n) return;
    int s = rowptr[node];
    const int end = rowptr[node + 1];

    float4 a0 = make_float4(0.f, 0.f, 0.f, 0.f), a1 = a0, a2 = a0, a3 = a0;

    for (; s + 7 < end; s += 8) {
        unsigned int c0 = csr[s];
        unsigned int c1 = csr[s + 1];
        unsigned int c2 = csr[s + 2];
        unsigned int c3 = csr[s + 3];
        unsigned int c4 = csr[s + 4];
        unsigned int c5 = csr[s + 5];
        unsigned int c6 = csr[s + 6];
        unsigned int c7 = csr[s + 7];
        gat_edge2(c0, XW2, lane32, &a0);
        gat_edge2(c1, XW2, lane32, &a1);
        gat_edge2(c2, XW2, lane32, &a2);
        gat_edge2(c3, XW2, lane32, &a3);
        gat_edge2(c4, XW2, lane32, &a0);
        gat_edge2(c5, XW2, lane32, &a1);
        gat_edge2(c6, XW2, lane32, &a2);
        gat_edge2(c7, XW2, lane32, &a3);
    }
    for (; s + 1 < end; s += 2) {
        unsigned int c0 = csr[s];
        unsigned int c1 = csr[s + 1];
        gat_edge2(c0, XW2, lane32, &a0);
        gat_edge2(c1, XW2, lane32, &a1);
    }
    if (s < end) {
        gat_edge2(csr[s], XW2, lane32, &a0);
    }

    float di = dinv[node];
    di = di * di;
    uint2 us = XW2[(size_t)node * 32 + lane32];
    float4 bv = ((const float4*)bias)[lane32];
    float4 o;
    o.x = eluf(a0.x + a1.x + a2.x + a3.x + bf_lo(us.x) * di + bv.x);
    o.y = eluf(a0.y + a1.y + a2.y + a3.y + bf_hi(us.x) * di + bv.y);
    o.z = eluf(a0.z + a1.z + a2.z + a3.z + bf_lo(us.y) * di + bv.z);
    o.w = eluf(a0.w + a1.w + a2.w + a3.w + bf_hi(us.y) * di + bv.w);
    if (RES) {
        uint2 rv = ((const uint2*)RES)[(size_t)node * 32 + lane32];
        o.x += h2f((unsigned short)(rv.x & 0xffffu));
        o.y += h2f((unsigned short)(rv.x >> 16));
        o.z += h2f((unsigned short)(rv.y & 0xffffu));
        o.w += h2f((unsigned short)(rv.y >> 16));
    }
    uint2 ov;
    ov.x = (unsigned int)f2h(o.x) | ((unsigned int)f2h(o.y) << 16);
    ov.y = (unsigned int)f2h(o.z) | ((unsigned int)f2h(o.w) << 16);
    ((uint2*)OUT)[(size_t)node * 32 + lane32] = ov;
}

// ---------------------------------------------------------------------------
// Layer-3 gather fused with head (half-wave per node; width-32 reduce).
// h3 never hits memory. RES (h2) fp16.
// ---------------------------------------------------------------------------
__global__ __launch_bounds__(256) void gather_head_k(const int* __restrict__ rowptr,
                                                     const unsigned int* __restrict__ csr,
                                                     const uint2* __restrict__ XW2,
                                                     const float* __restrict__ dinv,
                                                     const float* __restrict__ bias,
                                                     const unsigned short* __restrict__ RES,
                                                     const float* __restrict__ Wl,
                                                     const float* __restrict__ bl,
                                                     float* __restrict__ out, int n) {
    int half = threadIdx.x >> 5;
    int lane32 = threadIdx.x & 31;
    int node = blockIdx.x * 8 + half;
    if (node >= n) return;
    int s = rowptr[node];
    const int end = rowptr[node + 1];

    float4 a0 = make_float4(0.f, 0.f, 0.f, 0.f), a1 = a0, a2 = a0, a3 = a0;

    for (; s + 7 < end; s += 8) {
        unsigned int c0 = csr[s];
        unsigned int c1 = csr[s + 1];
        unsigned int c2 = csr[s + 2];
        unsigned int c3 = csr[s + 3];
        unsigned int c4 = csr[s + 4];
        unsigned int c5 = csr[s + 5];
        unsigned int c6 = csr[s + 6];
        unsigned int c7 = csr[s + 7];
        gat_edge2(c0, XW2, lane32, &a0);
        gat_edge2(c1, XW2, lane32, &a1);
        gat_edge2(c2, XW2, lane32, &a2);
        gat_edge2(c3, XW2, lane32, &a3);
        gat_edge2(c4, XW2, lane32, &a0);
        gat_edge2(c5, XW2, lane32, &a1);
        gat_edge2(c6, XW2, lane32, &a2);
        gat_edge2(c7, XW2, lane32, &a3);
    }
    for (; s + 1 < end; s += 2) {
        unsigned int c0 = csr[s];
        unsigned int c1 = csr[s + 1];
        gat_edge2(c0, XW2, lane32, &a0);
        gat_edge2(c1, XW2, lane32, &a1);
    }
    if (s < end) {
        gat_edge2(csr[s], XW2, lane32, &a0);
    }

    float di = dinv[node];
    di = di * di;
    uint2 us = XW2[(size_t)node * 32 + lane32];
    float4 bv = ((const float4*)bias)[lane32];
    uint2 rv = ((const uint2*)RES)[(size_t)node * 32 + lane32];
    float4 o;
    o.x = eluf(a0.x + a1.x + a2.x + a3.x + bf_lo(us.x) * di + bv.x) + h2f((unsigned short)(rv.x & 0xffffu));
    o.y = eluf(a0.y + a1.y + a2.y + a3.y + bf_hi(us.x) * di + bv.y) + h2f((unsigned short)(rv.x >> 16));
    o.z = eluf(a0.z + a1.z + a2.z + a3.z + bf_lo(us.y) * di + bv.z) + h2f((unsigned short)(rv.y & 0xffffu));
    o.w = eluf(a0.w + a1.w + a2.w + a3.w + bf_hi(us.y) * di + bv.w) + h2f((unsigned short)(rv.y >> 16));

    float4 wv = ((const float4*)Wl)[lane32];
    float acc = o.x * wv.x + o.y * wv.y + o.z * wv.z + o.w * wv.w;
#pragma unroll
    for (int off = 16; off > 0; off >>= 1) acc += __shfl_down(acc, off, 32);
    if (lane32 == 0) out[node] = 1.f / (1.f + expf(-(acc + bl[0])));
}

// ---------------------------------------------------------------------------
extern "C" void kernel_launch(void* const* d_in, const int* in_sizes, int n_in,
                              void* d_out, int out_size, void* d_ws, size_t ws_size,
                              hipStream_t stream) {
    const float* x  = (const float*)d_in[0];
    const int*   ei = (const int*)d_in[1];
    const float* ew = (const float*)d_in[2];
    const float* W1 = (const float*)d_in[3];
    const float* b1 = (const float*)d_in[4];
    const float* W2 = (const float*)d_in[5];
    const float* b2 = (const float*)d_in[6];
    const float* W3 = (const float*)d_in[7];
    const float* b3 = (const float*)d_in[8];
    const float* Wl = (const float*)d_in[9];
    const float* bl = (const float*)d_in[10];
    float* out = (float*)d_out;

    char* ws = (char*)d_ws;
    const size_t NHB = (size_t)N_NODES * HDIM * sizeof(float);  // 25.6 MB slots
    unsigned int*   A = (unsigned int*)(ws);          // XW in bf16 (12.8 MB used)
    unsigned short* B = (unsigned short*)(ws + NHB);  // h1 (fp16)
    unsigned short* C = (unsigned short*)(ws + 2 * NHB);  // h2 (fp16)
    char*  p    = ws + 3 * NHB;
    unsigned long long* pcnt = (unsigned long long*)p; p += sizeof(unsigned long long) * N_NODES;
    float* dinv    = (float*)p;            p += sizeof(float) * N_NODES;
    int*   src32   = (int*)p;              p += sizeof(int) * N_EDGES;
    unsigned int* drank = (unsigned int*)p; p += sizeof(unsigned int) * N_EDGES;
    int*   incl    = (int*)p;              p += sizeof(int) * N_NODES;
    int*   rowptr  = (int*)p;              p += sizeof(int) * (N_NODES + 2);
    unsigned int* csr = (unsigned int*)p;  p += sizeof(unsigned int) * N_EDGES;
    unsigned short* Wt1 = (unsigned short*)p; p += sizeof(unsigned short) * HDIM * HDIM;
    unsigned short* Wt2 = (unsigned short*)p; p += sizeof(unsigned short) * HDIM * HDIM;
    unsigned short* Wt3 = (unsigned short*)p; p += sizeof(unsigned short) * HDIM * HDIM;
    int*   bsum    = (int*)p;              p += sizeof(int) * 128;

    const int TB = 256;
    const int ggrid = (N_NODES + 7) / 8;   // 8 nodes per block (half-wave each)

    // --- preprocessing: [edges || wtrans] -> scan -> [reorder || gemm1] ---
    hipMemsetAsync(pcnt, 0, N_NODES * sizeof(unsigned long long), stream);
    edges_wtrans_k<<<EGRID + WT_NB, TB, 0, stream>>>(ei, ew, src32, drank, pcnt, N_EDGES,
                                                     W1, W2, W3, Wt1, Wt2, Wt3);
    scan1_k<<<SCAN_NB, SCAN_B, 0, stream>>>(pcnt, incl, bsum, dinv, N_NODES);
    scan3_k<<<SCAN_NB, SCAN_B, 0, stream>>>(pcnt, incl, bsum, rowptr, N_NODES, SCAN_NB);
    reorder_gemm_k<<<EGRID + GEMM_NB, TB, 0, stream>>>(src32, drank, ew, dinv, rowptr, csr, N_EDGES,
                                                       x, Wt1, (unsigned short*)A, N_NODES);

    // --- layer 1: h1 = elu(gcn(x, W1, b1)) -> B (fp16)  [gemm1 already done] ---
    gather_k<<<ggrid, TB, 0, stream>>>(rowptr, csr, (const uint2*)A, dinv, b1, nullptr, B, N_NODES);

    // --- layer 2: h2 = elu(gcn(h1, W2, b2)) + h1 -> C (fp16) ---
    mfma_gemm_k<true><<<GEMM_NB, TB, 0, stream>>>(B, Wt2, (unsigned short*)A, N_NODES);
    gather_k<<<ggrid, TB, 0, stream>>>(rowptr, csr, (const uint2*)A, dinv, b2, B, C, N_NODES);

    // --- layer 3 + head fused: out = sigmoid((elu(gcn(h2,W3,b3))+h2) @ Wl + bl) ---
    mfma_gemm_k<true><<<GEMM_NB, TB, 0, stream>>>(C, Wt3, (unsigned short*)A, N_NODES);
    gather_head_k<<<ggrid, TB, 0, stream>>>(rowptr, csr, (const uint2*)A, dinv, b3, C, Wl, bl, out, N_NODES);
}